// Round 16
// baseline (154.483 us; speedup 1.0000x reference)
//
#include <hip/hip_runtime.h>
#include <hip/hip_bf16.h>
#include <math.h>

// Outputs are FLOAT32. B=8, L=1024, K=30, F=128 -> flat offsets (f32 elements):
#define V_OFF    ((size_t)0)
#define E_OFF    ((size_t)1048576)
#define EIDX_OFF ((size_t)32505856)
#define BB_OFF   ((size_t)32751616)

#define K 30
#define NRBF 16
#define AH   232          // A-half LDS row stride in bf16
#define SSTR 132          // padded S stride (f32)

typedef __attribute__((ext_vector_type(8))) short bf16x8;
typedef __attribute__((ext_vector_type(4))) float f32x4;

// atom indices: N=0, Ca=1, C=2, CB=3, O=4
__device__ __constant__ int c_pairA[24] = {0,2,4,3,1,1,1,1,0,0,0,3,3,4,0,2,4,3,2,4,3,2,4,2};
__device__ __constant__ int c_pairB[24] = {0,2,4,3,0,2,4,3,2,4,3,2,4,2,1,1,1,1,0,0,0,3,3,4};

// mu_k * 0.8 * sqrt(log2(e)) for exp2-folded RBF
__device__ __constant__ float c_muS[16] = {
    1.92179871f, 3.20299785f, 4.48419699f, 5.76539613f, 7.04659527f, 8.32779441f,
    9.60899355f, 10.89019269f, 12.17139183f, 13.45259097f, 14.73379011f, 16.01498925f,
    17.29618839f, 18.57738753f, 19.85858667f, 21.13978581f};

__device__ __forceinline__ unsigned short f2bu(float f) {   // RNE f32->bf16 bits (finite)
    unsigned x = __float_as_uint(f);
    return (unsigned short)((x + 0x7fffu + ((x >> 16) & 1u)) >> 16);
}

// ---- DPP wave-64 reductions (result broadcast via lane-63 readlane) ----
__device__ __forceinline__ unsigned wave_umin64(unsigned x) {
    unsigned t;
    t = __builtin_amdgcn_update_dpp(x, x, 0x111, 0xf, 0xf, false); x = min(x, t);
    t = __builtin_amdgcn_update_dpp(x, x, 0x112, 0xf, 0xf, false); x = min(x, t);
    t = __builtin_amdgcn_update_dpp(x, x, 0x114, 0xf, 0xf, false); x = min(x, t);
    t = __builtin_amdgcn_update_dpp(x, x, 0x118, 0xf, 0xf, false); x = min(x, t);
    t = __builtin_amdgcn_update_dpp(x, x, 0x142, 0xf, 0xf, false); x = min(x, t);
    t = __builtin_amdgcn_update_dpp(x, x, 0x143, 0xf, 0xf, false); x = min(x, t);
    return (unsigned)__builtin_amdgcn_readlane((int)x, 63);
}
__device__ __forceinline__ unsigned wave_umax64(unsigned x) {
    unsigned t;
    t = __builtin_amdgcn_update_dpp(x, x, 0x111, 0xf, 0xf, false); x = max(x, t);
    t = __builtin_amdgcn_update_dpp(x, x, 0x112, 0xf, 0xf, false); x = max(x, t);
    t = __builtin_amdgcn_update_dpp(x, x, 0x114, 0xf, 0xf, false); x = max(x, t);
    t = __builtin_amdgcn_update_dpp(x, x, 0x118, 0xf, 0xf, false); x = max(x, t);
    t = __builtin_amdgcn_update_dpp(x, x, 0x142, 0xf, 0xf, false); x = max(x, t);
    t = __builtin_amdgcn_update_dpp(x, x, 0x143, 0xf, 0xf, false); x = max(x, t);
    return (unsigned)__builtin_amdgcn_readlane((int)x, 63);
}
__device__ __forceinline__ float wave_fadd64(float x) {
    float t;
    t = __int_as_float(__builtin_amdgcn_update_dpp(0, __float_as_int(x), 0x111, 0xf, 0xf, true)); x += t;
    t = __int_as_float(__builtin_amdgcn_update_dpp(0, __float_as_int(x), 0x112, 0xf, 0xf, true)); x += t;
    t = __int_as_float(__builtin_amdgcn_update_dpp(0, __float_as_int(x), 0x114, 0xf, 0xf, true)); x += t;
    t = __int_as_float(__builtin_amdgcn_update_dpp(0, __float_as_int(x), 0x118, 0xf, 0xf, true)); x += t;
    t = __int_as_float(__builtin_amdgcn_update_dpp(0, __float_as_int(x), 0x142, 0xf, 0xf, true)); x += t;
    t = __int_as_float(__builtin_amdgcn_update_dpp(0, __float_as_int(x), 0x143, 0xf, 0xf, true)); x += t;
    return __int_as_float(__builtin_amdgcn_readlane(__float_as_int(x), 63));
}
__device__ __forceinline__ unsigned mbcnt64(unsigned long long m) {
    return __builtin_amdgcn_mbcnt_hi((unsigned)(m >> 32),
           __builtin_amdgcn_mbcnt_lo((unsigned)m, 0u));
}
// 16-lane butterfly sum, all-DPP (xor1, xor2, half_mirror, row_mirror)
__device__ __forceinline__ float group16_fadd(float x) {
    float t;
    t = __int_as_float(__builtin_amdgcn_update_dpp(__float_as_int(x), __float_as_int(x), 0x0B1, 0xf, 0xf, false)); x += t; // quad_perm [1,0,3,2]
    t = __int_as_float(__builtin_amdgcn_update_dpp(__float_as_int(x), __float_as_int(x), 0x04E, 0xf, 0xf, false)); x += t; // quad_perm [2,3,0,1]
    t = __int_as_float(__builtin_amdgcn_update_dpp(__float_as_int(x), __float_as_int(x), 0x141, 0xf, 0xf, false)); x += t; // row_half_mirror (4<->8)
    t = __int_as_float(__builtin_amdgcn_update_dpp(__float_as_int(x), __float_as_int(x), 0x140, 0xf, 0xf, false)); x += t; // row_mirror (8<->16)
    return x;
}

__device__ __forceinline__ void norm_to(const float v[3], float o[3]) {
    float n = sqrtf(v[0]*v[0] + v[1]*v[1] + v[2]*v[2]);
    n = fmaxf(n, 1e-12f);
    o[0] = v[0]/n; o[1] = v[1]/n; o[2] = v[2]/n;
}
__device__ __forceinline__ void unit_diff(const float a[3], const float b[3], float o[3]) {
    float v[3] = {a[0]-b[0], a[1]-b[1], a[2]-b[2]};
    norm_to(v, o);
}
__device__ __forceinline__ void cross_unit(const float a[3], const float b[3], float o[3]) {
    float c[3] = {a[1]*b[2]-a[2]*b[1], a[2]*b[0]-a[0]*b[2], a[0]*b[1]-a[1]*b[0]};
    norm_to(c, o);
}

// ---------------- kernel 0: merged prep (Wb | rtab | ca4) ----------------
__global__ __launch_bounds__(256) void prep_kernel(
    const float* __restrict__ We, unsigned short* __restrict__ Wb,
    unsigned* __restrict__ rtab, const float* __restrict__ X,
    float4* __restrict__ ca4)
{
    const int bid = blockIdx.x, tid = threadIdx.x;
    if (bid < 13) {
        if (tid < 128) {
            const int s = bid, j = tid;
            unsigned* dst = (unsigned*)(Wb + ((size_t)(s*128 + j) << 5));
            #pragma unroll
            for (int m = 0; m < 16; ++m) {
                const int k0 = s*32 + 2*m;
                const unsigned lo = (k0   < 400) ? f2bu(We[(size_t)k0*128 + j])     : 0u;
                const unsigned hi = (k0+1 < 400) ? f2bu(We[(size_t)(k0+1)*128 + j]) : 0u;
                dst[m] = (hi << 16) | lo;
            }
        }
    } else if (bid < 29) {
        const int idx = (bid - 13)*256 + tid;   // 0..4095
        const float t1 = (idx * 0.02f) * 0.96089935f;
        unsigned* dst = rtab + ((size_t)idx << 3);
        #pragma unroll
        for (int m = 0; m < 8; ++m) {
            const float z0 = t1 - c_muS[2*m];
            const float z1 = t1 - c_muS[2*m+1];
            const float v0 = exp2f(-z0*z0);
            const float v1 = exp2f(-z1*z1);
            unsigned pk;
            asm("v_cvt_pk_bf16_f32 %0, %1, %2" : "=v"(pk) : "v"(v0), "v"(v1));
            dst[m] = pk;
        }
    } else {
        const int idx = (bid - 29)*256 + tid;   // 0..8191
        const float* p = X + (size_t)idx*15;
        ca4[idx] = make_float4(p[3], p[4], p[5], 0.f);
    }
}

// ---------------- kernel 1: fused top-k + edges + V + bb (512 threads / 8 waves) ----------------
__global__ __launch_bounds__(512, 8) void topk_edge_kernel(
    const float* __restrict__ X, const float* __restrict__ mask,
    const unsigned short* __restrict__ Wb, const float* __restrict__ Wp,
    const float* __restrict__ bp, const float* __restrict__ ge,
    const float* __restrict__ be, const float4* __restrict__ ca4,
    const unsigned* __restrict__ rtab,
    const float* __restrict__ Wn, const float* __restrict__ gn,
    const float* __restrict__ bn, float* __restrict__ out)
{
    const int blk = blockIdx.x;
    const int b = blk >> 10, i = blk & 1023;
    const int tid = threadIdx.x;
    const int w = tid >> 6, lane = tid & 63;

    __shared__ __align__(16) unsigned char uni_raw[K * SSTR * 4];  // 15840 B: surv / A-half / S union
    __shared__ float redf8[8];
    __shared__ unsigned redT8[8];
    __shared__ int   scount;
    __shared__ float nbA[K][15];
    __shared__ int   nj[K];
    __shared__ float dnbv[K];
    __shared__ float angf[3];
    unsigned short* A_lds = (unsigned short*)uni_raw;
    float* S = (float*)uni_raw;
    unsigned long long* surv = (unsigned long long*)uni_raw;   // phase-1 only

    if (tid == 0) scount = 0;

    // ---- phase 1: masked distances (coalesced float4 Ca); 2 candidates/thread ----
    const float4 me = ca4[(b << 10) + i];
    const float mi  = mask[(b << 10) + i];

    float dv_r[2], m2_r[2];
    float lmax = -1.f;
    #pragma unroll
    for (int m = 0; m < 2; ++m) {
        const int j = tid + (m << 9);
        const float4 cj = ca4[(b << 10) + j];
        const float dx = __fsub_rn(me.x, cj.x);
        const float dy = __fsub_rn(me.y, cj.y);
        const float dz = __fsub_rn(me.z, cj.z);
        // numpy association order: ((dx^2+dy^2)+dz^2)+1e-6
        const float ss = __fadd_rn(__fadd_rn(__fmul_rn(dx,dx), __fmul_rn(dy,dy)), __fmul_rn(dz,dz));
        const float dist = __fsqrt_rn(__fadd_rn(ss, 1e-6f));
        const float m2 = __fmul_rn(mi, mask[(b << 10) + j]);
        const float Dv = __fmul_rn(m2, dist);
        dv_r[m] = Dv; m2_r[m] = m2;
        lmax = fmaxf(lmax, Dv);
    }
    const float wmax = __uint_as_float(wave_umax64(__float_as_uint(lmax)));
    if (lane == 0) redf8[w] = wmax;
    __syncthreads();           // also covers scount init
    float Dmax = redf8[0];
    #pragma unroll
    for (int q = 1; q < 8; ++q) Dmax = fmaxf(Dmax, redf8[q]);

    unsigned va[2];
    #pragma unroll
    for (int m = 0; m < 2; ++m)
        va[m] = __float_as_uint(__fadd_rn(dv_r[m], __fmul_rn(__fsub_rn(1.f, m2_r[m]), Dmax)));

    // ---- Step A: per-wave threshold, TWO independent 2-extraction chains (dep depth 2) ----
    // >=2 elements <= each chain's 2nd value -> >=4 <= T_w per wave; 8 waves -> >=32 >= top-30.
    {
        unsigned a0 = va[0], b0 = va[1];
        const unsigned vA1 = wave_umin64(a0);
        const unsigned vB1 = wave_umin64(b0);
        a0 = (a0 == vA1) ? 0xffffffffu : a0;
        b0 = (b0 == vB1) ? 0xffffffffu : b0;
        const unsigned vA2 = wave_umin64(a0);
        const unsigned vB2 = wave_umin64(b0);
        if (lane == 0) redT8[w] = max(vA2, vB2);
    }
    __syncthreads();
    unsigned T = redT8[0];
    #pragma unroll
    for (int q = 1; q < 8; ++q) T = max(T, redT8[q]);

    // ---- Step B: compact survivors (value<<32|index) into LDS ----
    {
        unsigned long long mm0 = __ballot(va[0] <= T);
        unsigned long long mm1 = __ballot(va[1] <= T);
        const unsigned c0 = __popcll(mm0), c1 = __popcll(mm1);
        int old = 0;
        if (lane == 0) old = atomicAdd(&scount, (int)(c0 + c1));
        unsigned base = (unsigned)__builtin_amdgcn_readfirstlane(old);
        if (va[0] <= T) surv[base + mbcnt64(mm0)] = ((unsigned long long)va[0] << 32) | (unsigned)tid;
        base += c0;
        if (va[1] <= T) surv[base + mbcnt64(mm1)] = ((unsigned long long)va[1] << 32) | (unsigned)(tid + 512);
    }
    __syncthreads();
    const int N = scount;

    // ---- Step C: distributed exact rank selection (keys unique -> ranks a permutation) ----
    for (int base = 0; base < N; base += 512) {
        const int t = base + tid;
        if (t < N) {
            const unsigned long long mykey = surv[t];
            int rank = 0;
            #pragma unroll 4
            for (int u = 0; u < N; ++u) rank += (surv[u] < mykey) ? 1 : 0;
            if (rank < K) {
                const int j = (int)(mykey & 0xffffffffu);
                nj[rank] = j;
                dnbv[rank] = __uint_as_float((unsigned)(mykey >> 32));
                out[EIDX_OFF + (size_t)blk * K + rank] = (float)j;
            }
        }
    }
    __syncthreads();

    // ---- fetch neighbor atoms (450 items, single pass) ----
    if (tid < K*15) {
        const int e = tid / 15, r = tid - e*15;
        nbA[e][r] = X[((size_t)(b << 10) + nj[e])*15 + r];
    }
    __syncthreads();

    const float* sa = X + (size_t)blk * 15;
    f32x4 acc0 = {0,0,0,0}, acc1 = {0,0,0,0};
    const int ar = lane & 15;
    const int kg = (lane >> 4) * 8;
    const unsigned short* a_base = A_lds + ar*AH + kg;
    const unsigned short* a_base1 = a_base + 16*AH;
    const unsigned short* b_base = Wb + ((size_t)(w*16 + ar) << 5) + kg;   // wave w owns cols [16w,16w+16)

    // ================= PASS 1: g in [0,12), k-global [0,192) =================
    if (tid < K*12) {
        const int e = tid / 12, g = tid - e*12;
        float d;
        if (g == 0) d = dnbv[e];
        else {
            const int p = g - 1;
            const int aA = c_pairA[p], aB = c_pairB[p];
            const float dx = sa[aA*3+0] - nbA[e][aB*3+0];
            const float dy = sa[aA*3+1] - nbA[e][aB*3+1];
            const float dz = sa[aA*3+2] - nbA[e][aB*3+2];
            d = sqrtf(dx*dx + dy*dy + dz*dz + 1e-6f);
        }
        int idx = (int)__fmaf_rn(d, 50.f, 0.5f);
        idx = min(idx, 4095);
        const uint4* src = (const uint4*)(rtab + ((size_t)idx << 3));
        uint4* dst = (uint4*)(A_lds + e*AH + g*NRBF);
        dst[0] = src[0]; dst[1] = src[1];
    }
    __syncthreads();
    #pragma unroll
    for (int s = 0; s < 6; ++s) {
        const bf16x8 a0v = *reinterpret_cast<const bf16x8*>(a_base + s*32);
        const bf16x8 a1v = *reinterpret_cast<const bf16x8*>(a_base1 + s*32);
        const bf16x8 b0v = *reinterpret_cast<const bf16x8*>(b_base + (size_t)s*4096);
        acc0 = __builtin_amdgcn_mfma_f32_16x16x32_bf16(a0v, b0v, acc0, 0, 0, 0);
        acc1 = __builtin_amdgcn_mfma_f32_16x16x32_bf16(a1v, b0v, acc1, 0, 0, 0);
    }
    __syncthreads();   // pass-1 A reads complete

    // ================= PASS 2: g in [12,25), k-global [192,400)+pad =================
    if (tid < K*13) {
        const int e = tid / 13, gg = tid - e*13;
        const int p = 11 + gg;
        const int aA = c_pairA[p], aB = c_pairB[p];
        const float dx = sa[aA*3+0] - nbA[e][aB*3+0];
        const float dy = sa[aA*3+1] - nbA[e][aB*3+1];
        const float dz = sa[aA*3+2] - nbA[e][aB*3+2];
        const float d = sqrtf(dx*dx + dy*dy + dz*dz + 1e-6f);
        int idx = (int)__fmaf_rn(d, 50.f, 0.5f);
        idx = min(idx, 4095);
        const uint4* src = (const uint4*)(rtab + ((size_t)idx << 3));
        uint4* dst = (uint4*)(A_lds + e*AH + gg*NRBF);
        dst[0] = src[0]; dst[1] = src[1];
    }
    // zero k-local pad [208,224) for data rows 0..29 (240 items)
    if (tid < K*8) {
        const int e = tid >> 3, c = tid & 7;
        ((unsigned*)(A_lds + e*AH + 208))[c] = 0u;
    }
    __syncthreads();
    #pragma unroll
    for (int s = 0; s < 7; ++s) {
        const bf16x8 a0v = *reinterpret_cast<const bf16x8*>(a_base + s*32);
        const bf16x8 a1v = *reinterpret_cast<const bf16x8*>(a_base1 + s*32);
        const bf16x8 b0v = *reinterpret_cast<const bf16x8*>(b_base + (size_t)(6+s)*4096);
        acc0 = __builtin_amdgcn_mfma_f32_16x16x32_bf16(a0v, b0v, acc0, 0, 0, 0);
        acc1 = __builtin_amdgcn_mfma_f32_16x16x32_bf16(a1v, b0v, acc1, 0, 0, 0);
    }
    __syncthreads();   // pass-2 A reads complete; union region becomes S

    // ---- C-write with FUSED positional embedding + bias: S = acc + (Wp[off]+bp) ----
    {
        const int crow = (lane >> 4) * 4;
        const int ccol = w*16 + ar;
        const float bp0 = bp[ccol];
        #pragma unroll
        for (int r = 0; r < 4; ++r) {
            const int r0 = crow + r;
            if (r0 < K) {
                int off = i - nj[r0] + 32;
                off = off < 0 ? 0 : (off > 64 ? 64 : off);
                S[r0*SSTR + ccol] = acc0[r] + (Wp[(size_t)off*128 + ccol] + bp0);
            }
            const int r1 = 16 + crow + r;
            if (r1 < K) {
                int off = i - nj[r1] + 32;
                off = off < 0 ? 0 : (off > 64 ? 64 : off);
                S[r1*SSTR + ccol] = acc1[r] + (Wp[(size_t)off*128 + ccol] + bp0);
            }
        }
    }
    __syncthreads();

    // ---- per-edge LayerNorm: 16 threads per edge, 8 elems each ----
    {
        const int e = tid >> 4, sub = tid & 15;
        if (e < K) {
            const int j0 = sub*8;
            const float* row = S + e*SSTR + j0;
            float xv[8];
            float sum = 0.f;
            #pragma unroll
            for (int c = 0; c < 2; ++c) {
                const float4 q = ((const float4*)row)[c];
                xv[4*c+0] = q.x; xv[4*c+1] = q.y; xv[4*c+2] = q.z; xv[4*c+3] = q.w;
                sum += q.x + q.y + q.z + q.w;
            }
            const float mean = group16_fadd(sum) * (1.f/128.f);
            float vs = 0.f;
            #pragma unroll
            for (int c = 0; c < 8; ++c) { const float d = xv[c] - mean; xv[c] = d; vs = __fmaf_rn(d, d, vs); }
            const float inv = 1.f / __fsqrt_rn(group16_fadd(vs) * (1.f/128.f) + 1e-5f);
            float* op = out + E_OFF + ((size_t)blk * K + e) * 128 + j0;
            #pragma unroll
            for (int c = 0; c < 2; ++c) {
                const float4 g4 = ((const float4*)(ge + j0))[c];
                const float4 b4 = ((const float4*)(be + j0))[c];
                float4 o;
                o.x = xv[4*c+0] * inv * g4.x + b4.x;
                o.y = xv[4*c+1] * inv * g4.y + b4.y;
                o.z = xv[4*c+2] * inv * g4.z + b4.z;
                o.w = xv[4*c+3] * inv * g4.w + b4.w;
                ((float4*)op)[c] = o;
            }
        }
    }

    // ================= fused node features V + backbone bb =================
    if (tid < 3) {
        const int m = 3*i + tid;
        float dang = 0.f;
        if (m >= 1 && m <= 3*1024 - 3) {
            const int t = m - 1;
            float P[4][3];
            #pragma unroll
            for (int q = 0; q < 4; ++q) {
                const int s = t + q;
                const int ri = s / 3, ai = s - 3*ri;
                const float* p = X + (((size_t)b * 1024 + ri) * 5 + ai) * 3;
                P[q][0] = p[0]; P[q][1] = p[1]; P[q][2] = p[2];
            }
            float u2v[3], u1v[3], u0v[3];
            unit_diff(P[1], P[0], u2v);
            unit_diff(P[2], P[1], u1v);
            unit_diff(P[3], P[2], u0v);
            float n2v[3], n1v[3];
            cross_unit(u2v, u1v, n2v);
            cross_unit(u1v, u0v, n1v);
            float cosD = n2v[0]*n1v[0] + n2v[1]*n1v[1] + n2v[2]*n1v[2];
            cosD = fminf(fmaxf(cosD, -1.f + 1e-7f), 1.f - 1e-7f);
            float sg = u2v[0]*n1v[0] + u2v[1]*n1v[1] + u2v[2]*n1v[2];
            float s = (sg > 0.f) ? 1.f : ((sg < 0.f) ? -1.f : 0.f);
            dang = s * acosf(cosD);
        }
        angf[tid] = dang;
    }
    if (tid == 3) {
        float Nx=sa[0],  Ny=sa[1],  Nz=sa[2];
        float Cax=sa[3], Cay=sa[4], Caz=sa[5];
        float Cx=sa[6],  Cy=sa[7],  Cz=sa[8];
        float v1[3] = {Cx-Cax, Cy-Cay, Cz-Caz};
        float v2[3] = {Nx-Cax, Ny-Cay, Nz-Caz};
        float e1[3]; norm_to(v1, e1);
        float dd = e1[0]*v2[0] + e1[1]*v2[1] + e1[2]*v2[2];
        float u2[3] = {v2[0]-e1[0]*dd, v2[1]-e1[1]*dd, v2[2]-e1[2]*dd};
        float e2[3]; norm_to(u2, e2);
        float e3[3] = {e1[1]*e2[2]-e1[2]*e2[1], e1[2]*e2[0]-e1[0]*e2[2], e1[0]*e2[1]-e1[1]*e2[0]};
        float* bb = out + BB_OFF + (size_t)blk * 16;
        bb[0]=e1[0]; bb[1]=e1[1]; bb[2]=e1[2];  bb[3]=Cax;
        bb[4]=e2[0]; bb[5]=e2[1]; bb[6]=e2[2];  bb[7]=Cay;
        bb[8]=e3[0]; bb[9]=e3[1]; bb[10]=e3[2]; bb[11]=Caz;
        bb[12]=0.f; bb[13]=0.f; bb[14]=0.f; bb[15]=0.f;
    }
    __syncthreads();
    float xV = 0.f;
    if (tid < 128) {
        const float a0 = angf[0], a1 = angf[1], a2 = angf[2];
        const float feat[6] = {cosf(a0), cosf(a1), cosf(a2), sinf(a0), sinf(a1), sinf(a2)};
        #pragma unroll
        for (int f = 0; f < 6; ++f) xV += feat[f] * Wn[f*128 + tid];
        const float s = wave_fadd64(xV);
        if (lane == 0) redf8[w] = s;
    }
    __syncthreads();
    float xm = 0.f;
    if (tid < 128) {
        const float mean = (redf8[0] + redf8[1]) * (1.f/128.f);
        xm = xV - mean;
        const float vsum = wave_fadd64(xm*xm);
        if (lane == 0) redT8[w] = __float_as_uint(vsum);
    }
    __syncthreads();   // full-block barrier: compiler emits lgkmcnt wait; no divergent s_barrier
    if (tid < 128) {
        const float var = (__uint_as_float(redT8[0]) + __uint_as_float(redT8[1])) * (1.f/128.f);
        out[V_OFF + (size_t)blk * 128 + tid] = xm / __fsqrt_rn(var + 1e-5f) * gn[tid] + bn[tid];
    }
}

extern "C" void kernel_launch(void* const* d_in, const int* in_sizes, int n_in,
                              void* d_out, int out_size, void* d_ws, size_t ws_size,
                              hipStream_t stream) {
    const float* X    = (const float*)d_in[0];
    const float* mask = (const float*)d_in[1];
    // d_in[2] = Lvec (int32), unused
    const float* We   = (const float*)d_in[3];
    const float* Wn   = (const float*)d_in[4];
    const float* Wp   = (const float*)d_in[5];
    const float* bp   = (const float*)d_in[6];
    const float* gE   = (const float*)d_in[7];
    const float* bE   = (const float*)d_in[8];
    const float* gN   = (const float*)d_in[9];
    const float* bN   = (const float*)d_in[10];
    float* out = (float*)d_out;
    unsigned short* Wb = (unsigned short*)d_ws;                    // 106,496 B
    float4* ca4 = (float4*)((char*)d_ws + 106496);                 // 131,072 B
    unsigned* rtab = (unsigned*)((char*)d_ws + 106496 + 131072);   // 131,072 B

    hipLaunchKernelGGL(prep_kernel,      dim3(61),   dim3(256), 0, stream, We, Wb, rtab, X, ca4);
    hipLaunchKernelGGL(topk_edge_kernel, dim3(8192), dim3(512), 0, stream,
                       X, mask, Wb, Wp, bp, gE, bE, ca4, rtab, Wn, gN, bN, out);
}

// Round 17
// 131.023 us; speedup vs baseline: 1.1790x; 1.1790x over previous
//
#include <hip/hip_runtime.h>
#include <hip/hip_bf16.h>
#include <math.h>

// Outputs are FLOAT32. B=8, L=1024, K=30, F=128 -> flat offsets (f32 elements):
#define V_OFF    ((size_t)0)
#define E_OFF    ((size_t)1048576)
#define EIDX_OFF ((size_t)32505856)
#define BB_OFF   ((size_t)32751616)

#define K 30
#define NRBF 16
#define AH   232          // A-half LDS row stride in bf16
#define SSTR 132          // padded S stride (f32)

typedef __attribute__((ext_vector_type(8))) short bf16x8;
typedef __attribute__((ext_vector_type(4))) float f32x4;

// atom indices: N=0, Ca=1, C=2, CB=3, O=4
__device__ __constant__ int c_pairA[24] = {0,2,4,3,1,1,1,1,0,0,0,3,3,4,0,2,4,3,2,4,3,2,4,2};
__device__ __constant__ int c_pairB[24] = {0,2,4,3,0,2,4,3,2,4,3,2,4,2,1,1,1,1,0,0,0,3,3,4};

// mu_k * 0.8 * sqrt(log2(e)) for exp2-folded RBF
__device__ __constant__ float c_muS[16] = {
    1.92179871f, 3.20299785f, 4.48419699f, 5.76539613f, 7.04659527f, 8.32779441f,
    9.60899355f, 10.89019269f, 12.17139183f, 13.45259097f, 14.73379011f, 16.01498925f,
    17.29618839f, 18.57738753f, 19.85858667f, 21.13978581f};

__device__ __forceinline__ unsigned short f2bu(float f) {   // RNE f32->bf16 bits (finite)
    unsigned x = __float_as_uint(f);
    return (unsigned short)((x + 0x7fffu + ((x >> 16) & 1u)) >> 16);
}

// ---- DPP wave-64 reductions (result broadcast via lane-63 readlane) ----
__device__ __forceinline__ unsigned wave_umin64(unsigned x) {
    unsigned t;
    t = __builtin_amdgcn_update_dpp(x, x, 0x111, 0xf, 0xf, false); x = min(x, t);
    t = __builtin_amdgcn_update_dpp(x, x, 0x112, 0xf, 0xf, false); x = min(x, t);
    t = __builtin_amdgcn_update_dpp(x, x, 0x114, 0xf, 0xf, false); x = min(x, t);
    t = __builtin_amdgcn_update_dpp(x, x, 0x118, 0xf, 0xf, false); x = min(x, t);
    t = __builtin_amdgcn_update_dpp(x, x, 0x142, 0xf, 0xf, false); x = min(x, t);
    t = __builtin_amdgcn_update_dpp(x, x, 0x143, 0xf, 0xf, false); x = min(x, t);
    return (unsigned)__builtin_amdgcn_readlane((int)x, 63);
}
__device__ __forceinline__ unsigned wave_umax64(unsigned x) {
    unsigned t;
    t = __builtin_amdgcn_update_dpp(x, x, 0x111, 0xf, 0xf, false); x = max(x, t);
    t = __builtin_amdgcn_update_dpp(x, x, 0x112, 0xf, 0xf, false); x = max(x, t);
    t = __builtin_amdgcn_update_dpp(x, x, 0x114, 0xf, 0xf, false); x = max(x, t);
    t = __builtin_amdgcn_update_dpp(x, x, 0x118, 0xf, 0xf, false); x = max(x, t);
    t = __builtin_amdgcn_update_dpp(x, x, 0x142, 0xf, 0xf, false); x = max(x, t);
    t = __builtin_amdgcn_update_dpp(x, x, 0x143, 0xf, 0xf, false); x = max(x, t);
    return (unsigned)__builtin_amdgcn_readlane((int)x, 63);
}
__device__ __forceinline__ float wave_fadd64(float x) {
    float t;
    t = __int_as_float(__builtin_amdgcn_update_dpp(0, __float_as_int(x), 0x111, 0xf, 0xf, true)); x += t;
    t = __int_as_float(__builtin_amdgcn_update_dpp(0, __float_as_int(x), 0x112, 0xf, 0xf, true)); x += t;
    t = __int_as_float(__builtin_amdgcn_update_dpp(0, __float_as_int(x), 0x114, 0xf, 0xf, true)); x += t;
    t = __int_as_float(__builtin_amdgcn_update_dpp(0, __float_as_int(x), 0x118, 0xf, 0xf, true)); x += t;
    t = __int_as_float(__builtin_amdgcn_update_dpp(0, __float_as_int(x), 0x142, 0xf, 0xf, true)); x += t;
    t = __int_as_float(__builtin_amdgcn_update_dpp(0, __float_as_int(x), 0x143, 0xf, 0xf, true)); x += t;
    return __int_as_float(__builtin_amdgcn_readlane(__float_as_int(x), 63));
}
__device__ __forceinline__ unsigned mbcnt64(unsigned long long m) {
    return __builtin_amdgcn_mbcnt_hi((unsigned)(m >> 32),
           __builtin_amdgcn_mbcnt_lo((unsigned)m, 0u));
}
// 8-lane butterfly sum, all-DPP (xor1, xor2, then row_half_mirror for the 4<->8 cross)
__device__ __forceinline__ float group8_fadd(float x) {
    float t;
    t = __int_as_float(__builtin_amdgcn_update_dpp(__float_as_int(x), __float_as_int(x), 0x0B1, 0xf, 0xf, false)); x += t; // quad_perm [1,0,3,2]
    t = __int_as_float(__builtin_amdgcn_update_dpp(__float_as_int(x), __float_as_int(x), 0x04E, 0xf, 0xf, false)); x += t; // quad_perm [2,3,0,1]
    t = __int_as_float(__builtin_amdgcn_update_dpp(__float_as_int(x), __float_as_int(x), 0x141, 0xf, 0xf, false)); x += t; // row_half_mirror
    return x;
}

__device__ __forceinline__ void norm_to(const float v[3], float o[3]) {
    float n = sqrtf(v[0]*v[0] + v[1]*v[1] + v[2]*v[2]);
    n = fmaxf(n, 1e-12f);
    o[0] = v[0]/n; o[1] = v[1]/n; o[2] = v[2]/n;
}
__device__ __forceinline__ void unit_diff(const float a[3], const float b[3], float o[3]) {
    float v[3] = {a[0]-b[0], a[1]-b[1], a[2]-b[2]};
    norm_to(v, o);
}
__device__ __forceinline__ void cross_unit(const float a[3], const float b[3], float o[3]) {
    float c[3] = {a[1]*b[2]-a[2]*b[1], a[2]*b[0]-a[0]*b[2], a[0]*b[1]-a[1]*b[0]};
    norm_to(c, o);
}

// ---------------- kernel 0: merged prep (Wb | rtab | ca4) ----------------
// blocks 0..12: We->Wb repack; 13..28: rbf table; 29..60: Ca float4 pack
__global__ __launch_bounds__(256) void prep_kernel(
    const float* __restrict__ We, unsigned short* __restrict__ Wb,
    unsigned* __restrict__ rtab, const float* __restrict__ X,
    float4* __restrict__ ca4)
{
    const int bid = blockIdx.x, tid = threadIdx.x;
    if (bid < 13) {
        if (tid < 128) {
            const int s = bid, j = tid;
            unsigned* dst = (unsigned*)(Wb + ((size_t)(s*128 + j) << 5));
            #pragma unroll
            for (int m = 0; m < 16; ++m) {
                const int k0 = s*32 + 2*m;
                const unsigned lo = (k0   < 400) ? f2bu(We[(size_t)k0*128 + j])     : 0u;
                const unsigned hi = (k0+1 < 400) ? f2bu(We[(size_t)(k0+1)*128 + j]) : 0u;
                dst[m] = (hi << 16) | lo;
            }
        }
    } else if (bid < 29) {
        const int idx = (bid - 13)*256 + tid;   // 0..4095
        const float t1 = (idx * 0.02f) * 0.96089935f;
        unsigned* dst = rtab + ((size_t)idx << 3);
        #pragma unroll
        for (int m = 0; m < 8; ++m) {
            const float z0 = t1 - c_muS[2*m];
            const float z1 = t1 - c_muS[2*m+1];
            const float v0 = exp2f(-z0*z0);
            const float v1 = exp2f(-z1*z1);
            unsigned pk;
            asm("v_cvt_pk_bf16_f32 %0, %1, %2" : "=v"(pk) : "v"(v0), "v"(v1));
            dst[m] = pk;
        }
    } else {
        const int idx = (bid - 29)*256 + tid;   // 0..8191
        const float* p = X + (size_t)idx*15;
        ca4[idx] = make_float4(p[3], p[4], p[5], 0.f);
    }
}

// ---------------- kernel 1: fused top-k + edges + node features + bb ----------------
__global__ __launch_bounds__(256, 8) void topk_edge_kernel(
    const float* __restrict__ X, const float* __restrict__ mask,
    const unsigned short* __restrict__ Wb, const float* __restrict__ Wp,
    const float* __restrict__ bp, const float* __restrict__ ge,
    const float* __restrict__ be, const float4* __restrict__ ca4,
    const unsigned* __restrict__ rtab,
    const float* __restrict__ Wn, const float* __restrict__ gn,
    const float* __restrict__ bn, float* __restrict__ out)
{
    const int blk = blockIdx.x;
    const int b = blk >> 10, i = blk & 1023;
    const int tid = threadIdx.x;
    const int w = tid >> 6, lane = tid & 63;

    __shared__ __align__(16) unsigned char uni_raw[K * SSTR * 4];  // 15840 B: surv / A-half / S union
    __shared__ float redf4[4];
    __shared__ unsigned redT[4];
    __shared__ int   scount;
    __shared__ float nbA[K][15];
    __shared__ int   nj[K];
    __shared__ float dnbv[K];
    __shared__ float angf[3];
    unsigned short* A_lds = (unsigned short*)uni_raw;
    float* S = (float*)uni_raw;
    unsigned long long* surv = (unsigned long long*)uni_raw;   // phase-1 only

    if (tid == 0) scount = 0;

    // ---- phase 1: masked distances (coalesced float4 Ca) ----
    const float4 me = ca4[(b << 10) + i];
    const float mi  = mask[(b << 10) + i];

    float dv_r[4], m2_r[4];
    float lmax = -1.f;
    #pragma unroll
    for (int m = 0; m < 4; ++m) {
        const int j = tid + (m << 8);
        const float4 cj = ca4[(b << 10) + j];
        const float dx = __fsub_rn(me.x, cj.x);
        const float dy = __fsub_rn(me.y, cj.y);
        const float dz = __fsub_rn(me.z, cj.z);
        // numpy association order: ((dx^2+dy^2)+dz^2)+1e-6
        const float ss = __fadd_rn(__fadd_rn(__fmul_rn(dx,dx), __fmul_rn(dy,dy)), __fmul_rn(dz,dz));
        const float dist = __fsqrt_rn(__fadd_rn(ss, 1e-6f));
        const float m2 = __fmul_rn(mi, mask[(b << 10) + j]);
        const float Dv = __fmul_rn(m2, dist);
        dv_r[m] = Dv; m2_r[m] = m2;
        lmax = fmaxf(lmax, Dv);
    }
    const float wmax = __uint_as_float(wave_umax64(__float_as_uint(lmax)));
    if (lane == 0) redf4[w] = wmax;
    __syncthreads();           // also covers scount init
    const float Dmax = fmaxf(fmaxf(redf4[0], redf4[1]), fmaxf(redf4[2], redf4[3]));

    unsigned va[4];
    #pragma unroll
    for (int m = 0; m < 4; ++m)
        va[m] = __float_as_uint(__fadd_rn(dv_r[m], __fmul_rn(__fsub_rn(1.f, m2_r[m]), Dmax)));

    // ---- Step A: per-wave threshold via TWO independent 4-extraction chains (ILP 2) ----
    // >=4 candidates <= each chain's 4th value -> >=8 <= T_w per wave -> >=32 per block >= top-30.
    {
        unsigned a0 = va[0], a1 = va[1];
        unsigned b0 = va[2], b1 = va[3];
        unsigned vA = 0, vB = 0;
        #pragma unroll
        for (int k = 0; k < 4; ++k) {
            const unsigned hA = min(a0, a1);
            const unsigned hB = min(b0, b1);
            vA = wave_umin64(hA);
            vB = wave_umin64(hB);
            a0 = (a0 == vA) ? 0xffffffffu : a0;
            a1 = (a1 == vA) ? 0xffffffffu : a1;
            b0 = (b0 == vB) ? 0xffffffffu : b0;
            b1 = (b1 == vB) ? 0xffffffffu : b1;
        }
        if (lane == 0) redT[w] = max(vA, vB);
    }
    __syncthreads();
    const unsigned T = max(max(redT[0], redT[1]), max(redT[2], redT[3]));

    // ---- Step B: compact survivors (value<<32|index) into LDS ----
    {
        unsigned long long mm0 = __ballot(va[0] <= T);
        unsigned long long mm1 = __ballot(va[1] <= T);
        unsigned long long mm2 = __ballot(va[2] <= T);
        unsigned long long mm3 = __ballot(va[3] <= T);
        const unsigned c0 = __popcll(mm0), c1 = __popcll(mm1);
        const unsigned c2 = __popcll(mm2), c3 = __popcll(mm3);
        int old = 0;
        if (lane == 0) old = atomicAdd(&scount, (int)(c0 + c1 + c2 + c3));
        unsigned base = (unsigned)__builtin_amdgcn_readfirstlane(old);
        if (va[0] <= T) surv[base + mbcnt64(mm0)] = ((unsigned long long)va[0] << 32) | (unsigned)tid;
        base += c0;
        if (va[1] <= T) surv[base + mbcnt64(mm1)] = ((unsigned long long)va[1] << 32) | (unsigned)(tid + 256);
        base += c1;
        if (va[2] <= T) surv[base + mbcnt64(mm2)] = ((unsigned long long)va[2] << 32) | (unsigned)(tid + 512);
        base += c2;
        if (va[3] <= T) surv[base + mbcnt64(mm3)] = ((unsigned long long)va[3] << 32) | (unsigned)(tid + 768);
    }
    __syncthreads();
    const int N = scount;

    // ---- Step C: distributed exact rank selection (keys unique -> ranks a permutation) ----
    for (int base = 0; base < N; base += 256) {
        const int t = base + tid;
        if (t < N) {
            const unsigned long long mykey = surv[t];
            int rank = 0;
            #pragma unroll 4
            for (int u = 0; u < N; ++u) rank += (surv[u] < mykey) ? 1 : 0;
            if (rank < K) {
                const int j = (int)(mykey & 0xffffffffu);
                nj[rank] = j;
                dnbv[rank] = __uint_as_float((unsigned)(mykey >> 32));
                out[EIDX_OFF + (size_t)blk * K + rank] = (float)j;
            }
        }
    }
    __syncthreads();

    // ---- fetch neighbor atoms ----
    for (int t = tid; t < K*15; t += 256) {
        const int e = t / 15, r = t - e*15;
        nbA[e][r] = X[((size_t)(b << 10) + nj[e])*15 + r];
    }
    __syncthreads();

    const float* sa = X + (size_t)blk * 15;
    f32x4 acc00 = {0,0,0,0}, acc01 = {0,0,0,0}, acc10 = {0,0,0,0}, acc11 = {0,0,0,0};
    const int ar = lane & 15;
    const int kg = (lane >> 4) * 8;
    const unsigned short* a_base = A_lds + ar*AH + kg;
    const unsigned short* a_base1 = a_base + 16*AH;
    const unsigned short* b_base = Wb + ((size_t)(w*32 + ar) << 5) + kg;

    // ================= PASS 1: g in [0,12), k-global [0,192) =================
    for (int t = tid; t < K*12; t += 256) {
        const int e = t / 12, g = t - e*12;
        float d;
        if (g == 0) d = dnbv[e];
        else {
            const int p = g - 1;
            const int aA = c_pairA[p], aB = c_pairB[p];
            const float dx = sa[aA*3+0] - nbA[e][aB*3+0];
            const float dy = sa[aA*3+1] - nbA[e][aB*3+1];
            const float dz = sa[aA*3+2] - nbA[e][aB*3+2];
            d = sqrtf(dx*dx + dy*dy + dz*dz + 1e-6f);
        }
        int idx = (int)__fmaf_rn(d, 50.f, 0.5f);
        idx = min(idx, 4095);
        const uint4* src = (const uint4*)(rtab + ((size_t)idx << 3));
        uint4* dst = (uint4*)(A_lds + e*AH + g*NRBF);
        dst[0] = src[0]; dst[1] = src[1];
    }
    __syncthreads();
    #pragma unroll
    for (int s = 0; s < 6; ++s) {
        const bf16x8 a0 = *reinterpret_cast<const bf16x8*>(a_base + s*32);
        const bf16x8 a1 = *reinterpret_cast<const bf16x8*>(a_base1 + s*32);
        const bf16x8 b0 = *reinterpret_cast<const bf16x8*>(b_base + (size_t)s*4096);
        const bf16x8 b1 = *reinterpret_cast<const bf16x8*>(b_base + (size_t)s*4096 + 512);
        acc00 = __builtin_amdgcn_mfma_f32_16x16x32_bf16(a0, b0, acc00, 0, 0, 0);
        acc01 = __builtin_amdgcn_mfma_f32_16x16x32_bf16(a0, b1, acc01, 0, 0, 0);
        acc10 = __builtin_amdgcn_mfma_f32_16x16x32_bf16(a1, b0, acc10, 0, 0, 0);
        acc11 = __builtin_amdgcn_mfma_f32_16x16x32_bf16(a1, b1, acc11, 0, 0, 0);
    }
    __syncthreads();   // pass-1 A reads complete

    // ================= PASS 2: g in [12,25), k-global [192,400)+pad =================
    for (int t = tid; t < K*13; t += 256) {
        const int e = t / 13, gg = t - e*13;
        const int p = 11 + gg;
        const int aA = c_pairA[p], aB = c_pairB[p];
        const float dx = sa[aA*3+0] - nbA[e][aB*3+0];
        const float dy = sa[aA*3+1] - nbA[e][aB*3+1];
        const float dz = sa[aA*3+2] - nbA[e][aB*3+2];
        const float d = sqrtf(dx*dx + dy*dy + dz*dz + 1e-6f);
        int idx = (int)__fmaf_rn(d, 50.f, 0.5f);
        idx = min(idx, 4095);
        const uint4* src = (const uint4*)(rtab + ((size_t)idx << 3));
        uint4* dst = (uint4*)(A_lds + e*AH + gg*NRBF);
        dst[0] = src[0]; dst[1] = src[1];
    }
    // zero k-local pad [208,224) for data rows 0..29
    for (int t = tid; t < K*8; t += 256) {
        const int e = t >> 3, c = t & 7;
        ((unsigned*)(A_lds + e*AH + 208))[c] = 0u;
    }
    __syncthreads();
    #pragma unroll
    for (int s = 0; s < 7; ++s) {
        const bf16x8 a0 = *reinterpret_cast<const bf16x8*>(a_base + s*32);
        const bf16x8 a1 = *reinterpret_cast<const bf16x8*>(a_base1 + s*32);
        const bf16x8 b0 = *reinterpret_cast<const bf16x8*>(b_base + (size_t)(6+s)*4096);
        const bf16x8 b1 = *reinterpret_cast<const bf16x8*>(b_base + (size_t)(6+s)*4096 + 512);
        acc00 = __builtin_amdgcn_mfma_f32_16x16x32_bf16(a0, b0, acc00, 0, 0, 0);
        acc01 = __builtin_amdgcn_mfma_f32_16x16x32_bf16(a0, b1, acc01, 0, 0, 0);
        acc10 = __builtin_amdgcn_mfma_f32_16x16x32_bf16(a1, b0, acc10, 0, 0, 0);
        acc11 = __builtin_amdgcn_mfma_f32_16x16x32_bf16(a1, b1, acc11, 0, 0, 0);
    }
    __syncthreads();   // pass-2 A reads complete; union region becomes S

    // ---- C-write with FUSED positional embedding + bias: S = acc + (Wp[off]+bp) ----
    // bit-identical to the old separate phase (old: S=acc; S += (wp+bq)).
    {
        const int crow = (lane >> 4) * 4;
        const int ccol = w*32 + (lane & 15);
        const float bp0 = bp[ccol], bp1 = bp[ccol + 16];
        #pragma unroll
        for (int r = 0; r < 4; ++r) {
            const int r0 = crow + r;
            if (r0 < K) {
                int off = i - nj[r0] + 32;
                off = off < 0 ? 0 : (off > 64 ? 64 : off);
                const float* wr = Wp + (size_t)off*128;
                S[r0*SSTR + ccol]      = acc00[r] + (wr[ccol]      + bp0);
                S[r0*SSTR + ccol + 16] = acc01[r] + (wr[ccol + 16] + bp1);
            }
            const int r1 = 16 + crow + r;
            if (r1 < K) {
                int off = i - nj[r1] + 32;
                off = off < 0 ? 0 : (off > 64 ? 64 : off);
                const float* wr = Wp + (size_t)off*128;
                S[r1*SSTR + ccol]      = acc10[r] + (wr[ccol]      + bp0);
                S[r1*SSTR + ccol + 16] = acc11[r] + (wr[ccol + 16] + bp1);
            }
        }
    }
    __syncthreads();

    // ---- per-edge LayerNorm: one thread per (edge, 16-elem strip) ----
    {
        const int e = tid >> 3, s8 = tid & 7;
        if (e < K) {
            const float* row = S + e*SSTR + s8*16;
            float xv[16];
            float sum = 0.f;
            #pragma unroll
            for (int c = 0; c < 4; ++c) {
                const float4 q = ((const float4*)row)[c];
                xv[4*c+0] = q.x; xv[4*c+1] = q.y; xv[4*c+2] = q.z; xv[4*c+3] = q.w;
                sum += q.x + q.y + q.z + q.w;
            }
            const float mean = group8_fadd(sum) * (1.f/128.f);
            float vs = 0.f;
            #pragma unroll
            for (int c = 0; c < 16; ++c) { const float d = xv[c] - mean; xv[c] = d; vs = __fmaf_rn(d, d, vs); }
            const float inv = 1.f / __fsqrt_rn(group8_fadd(vs) * (1.f/128.f) + 1e-5f);
            const int j0 = s8*16;
            float* op = out + E_OFF + ((size_t)blk * K + e) * 128 + j0;
            #pragma unroll
            for (int c = 0; c < 4; ++c) {
                const float4 g4 = ((const float4*)(ge + j0))[c];
                const float4 b4 = ((const float4*)(be + j0))[c];
                float4 o;
                o.x = xv[4*c+0] * inv * g4.x + b4.x;
                o.y = xv[4*c+1] * inv * g4.y + b4.y;
                o.z = xv[4*c+2] * inv * g4.z + b4.z;
                o.w = xv[4*c+3] * inv * g4.w + b4.w;
                ((float4*)op)[c] = o;
            }
        }
    }

    // ================= fused node features V + backbone bb =================
    if (tid < 3) {
        const int m = 3*i + tid;
        float dang = 0.f;
        if (m >= 1 && m <= 3*1024 - 3) {
            const int t = m - 1;
            float P[4][3];
            #pragma unroll
            for (int q = 0; q < 4; ++q) {
                const int s = t + q;
                const int ri = s / 3, ai = s - 3*ri;
                const float* p = X + (((size_t)b * 1024 + ri) * 5 + ai) * 3;
                P[q][0] = p[0]; P[q][1] = p[1]; P[q][2] = p[2];
            }
            float u2v[3], u1v[3], u0v[3];
            unit_diff(P[1], P[0], u2v);
            unit_diff(P[2], P[1], u1v);
            unit_diff(P[3], P[2], u0v);
            float n2v[3], n1v[3];
            cross_unit(u2v, u1v, n2v);
            cross_unit(u1v, u0v, n1v);
            float cosD = n2v[0]*n1v[0] + n2v[1]*n1v[1] + n2v[2]*n1v[2];
            cosD = fminf(fmaxf(cosD, -1.f + 1e-7f), 1.f - 1e-7f);
            float sg = u2v[0]*n1v[0] + u2v[1]*n1v[1] + u2v[2]*n1v[2];
            float s = (sg > 0.f) ? 1.f : ((sg < 0.f) ? -1.f : 0.f);
            dang = s * acosf(cosD);
        }
        angf[tid] = dang;
    }
    if (tid == 3) {
        float Nx=sa[0],  Ny=sa[1],  Nz=sa[2];
        float Cax=sa[3], Cay=sa[4], Caz=sa[5];
        float Cx=sa[6],  Cy=sa[7],  Cz=sa[8];
        float v1[3] = {Cx-Cax, Cy-Cay, Cz-Caz};
        float v2[3] = {Nx-Cax, Ny-Cay, Nz-Caz};
        float e1[3]; norm_to(v1, e1);
        float dd = e1[0]*v2[0] + e1[1]*v2[1] + e1[2]*v2[2];
        float u2[3] = {v2[0]-e1[0]*dd, v2[1]-e1[1]*dd, v2[2]-e1[2]*dd};
        float e2[3]; norm_to(u2, e2);
        float e3[3] = {e1[1]*e2[2]-e1[2]*e2[1], e1[2]*e2[0]-e1[0]*e2[2], e1[0]*e2[1]-e1[1]*e2[0]};
        float* bb = out + BB_OFF + (size_t)blk * 16;
        bb[0]=e1[0]; bb[1]=e1[1]; bb[2]=e1[2];  bb[3]=Cax;
        bb[4]=e2[0]; bb[5]=e2[1]; bb[6]=e2[2];  bb[7]=Cay;
        bb[8]=e3[0]; bb[9]=e3[1]; bb[10]=e3[2]; bb[11]=Caz;
        bb[12]=0.f; bb[13]=0.f; bb[14]=0.f; bb[15]=0.f;
    }
    __syncthreads();
    float xV = 0.f;
    if (tid < 128) {
        const float a0 = angf[0], a1 = angf[1], a2 = angf[2];
        const float feat[6] = {cosf(a0), cosf(a1), cosf(a2), sinf(a0), sinf(a1), sinf(a2)};
        #pragma unroll
        for (int f = 0; f < 6; ++f) xV += feat[f] * Wn[f*128 + tid];
        const float s = wave_fadd64(xV);
        if (lane == 0) redf4[w] = s;
    }
    __syncthreads();
    float xm = 0.f;
    if (tid < 128) {
        const float mean = (redf4[0] + redf4[1]) * (1.f/128.f);
        xm = xV - mean;
        const float vsum = wave_fadd64(xm*xm);
        if (lane == 0) redT[w] = __float_as_uint(vsum);
    }
    __syncthreads();   // full-block barrier: compiler emits lgkmcnt wait; no divergent s_barrier
    if (tid < 128) {
        const float var = (__uint_as_float(redT[0]) + __uint_as_float(redT[1])) * (1.f/128.f);
        out[V_OFF + (size_t)blk * 128 + tid] = xm / __fsqrt_rn(var + 1e-5f) * gn[tid] + bn[tid];
    }
}

extern "C" void kernel_launch(void* const* d_in, const int* in_sizes, int n_in,
                              void* d_out, int out_size, void* d_ws, size_t ws_size,
                              hipStream_t stream) {
    const float* X    = (const float*)d_in[0];
    const float* mask = (const float*)d_in[1];
    // d_in[2] = Lvec (int32), unused
    const float* We   = (const float*)d_in[3];
    const float* Wn   = (const float*)d_in[4];
    const float* Wp   = (const float*)d_in[5];
    const float* bp   = (const float*)d_in[6];
    const float* gE   = (const float*)d_in[7];
    const float* bE   = (const float*)d_in[8];
    const float* gN   = (const float*)d_in[9];
    const float* bN   = (const float*)d_in[10];
    float* out = (float*)d_out;
    unsigned short* Wb = (unsigned short*)d_ws;                    // 106,496 B
    float4* ca4 = (float4*)((char*)d_ws + 106496);                 // 131,072 B
    unsigned* rtab = (unsigned*)((char*)d_ws + 106496 + 131072);   // 131,072 B

    hipLaunchKernelGGL(prep_kernel,      dim3(61),   dim3(256), 0, stream, We, Wb, rtab, X, ca4);
    hipLaunchKernelGGL(topk_edge_kernel, dim3(8192), dim3(256), 0, stream,
                       X, mask, Wb, Wp, bp, gE, bE, ca4, rtab, Wn, gN, bN, out);
}